// Round 1
// 1717.491 us; speedup vs baseline: 1.1719x; 1.1719x over previous
//
#include <hip/hip_runtime.h>
#include <hip/hip_bf16.h>
#include <stdint.h>

// ---------------------------------------------------------------------------
// GraphEncoder. Round 4: ring-buffered producer/consumer persistent kernel.
//  - ws_size < 307MB made the old "new path" dead code; this path needs ~56MB
//    (guaranteed, since the legacy path at ~105.8MB ran on this harness).
//  - 192 producer blocks fuse embed-gather + elu GEMM + P/Q GEMMs per
//    (step,batch) chunk into a 12-step ring (mem array never materialized).
//  - 64 consumer blocks run the scan with 2 phases/step (att || hW-GEMM, then
//    x/gi/GRU), synced by a broadcast barrier (per-block flag lines + 64-lane
//    parallel poll) instead of one contended fetch-add counter.
//  - All cross-block data goes through agent-scope atomic ld/st (MALL-coherent),
//    the pattern already verified by the legacy kernel.
// ---------------------------------------------------------------------------

typedef __bf16 bf16_t;
typedef __bf16 bf16x8 __attribute__((ext_vector_type(8)));
typedef float  f32x4  __attribute__((ext_vector_type(4)));

#define MFMA16(a,b,c) __builtin_amdgcn_mfma_f32_16x16x32_bf16((a),(b),(c),0,0,0)

// ======================= v4 (ring) workspace ================================
// ring chunk (per step i, batch g): bf16[65536] = P[64][512] ; Qt[512][64]
static constexpr int    RW     = 12;                      // ring depth (steps)
static constexpr size_t V_RING = 0;
static constexpr size_t V_WEH  = V_RING + (size_t)RW*32*65536*2;  // 50,331,648
static constexpr size_t V_W2   = V_WEH + 524288;   // bf16 [1024][512]: Win^T ; Wc
static constexpr size_t V_WH   = V_W2  + 1048576;  // bf16 [2048][512]: Whh ; Wh2
static constexpr size_t V_WI   = V_WH  + 2097152;  // bf16 [1536][512]
static constexpr size_t V_LEN  = V_WI  + 1572864;  // int [1536]
static constexpr size_t V_H    = V_LEN + 8192;     // f32 [32][512]
static constexpr size_t V_HBF  = V_H   + 65536;    // bf16 [32][512]
static constexpr size_t V_GH   = V_HBF + 32768;    // f32 [32][1536]
static constexpr size_t V_HW2  = V_GH  + 196608;   // f32 [32][512]
static constexpr size_t V_XC   = V_HW2 + 65536;    // f32 [32][512]
static constexpr size_t V_FLG  = V_XC  + 65536;    // u32[64*16] consumer flags
static constexpr size_t V_REL  = V_FLG + 4096;     // u32 release counter
static constexpr size_t V_PD   = V_REL + 64;       // u32[1536] chunk-done flags
static constexpr size_t WS_V4  = V_PD  + 6144;     // ~56.0 MB

// ======================= legacy workspace layout ============================
static constexpr size_t L_MEM   = 0;
static constexpr size_t L_WA    = 100663296;
static constexpr size_t L_WOUT  = L_WA + 2097152;
static constexpr size_t L_WIH   = L_WOUT + 1048576;
static constexpr size_t L_LEN   = L_WIH + 1572864;
static constexpr size_t L_H     = L_LEN + 8192;
static constexpr size_t L_HBF   = L_H + 65536;
static constexpr size_t L_Q     = L_HBF + 32768;
static constexpr size_t L_GH    = L_Q + 65536;
static constexpr size_t L_CBF   = L_GH + 196608;
static constexpr size_t L_XBF   = L_CBF + 32768;
static constexpr size_t L_BAR   = L_XBF + 32768;
static constexpr size_t WS_LEG  = L_BAR + 256;

// ---- helpers ----
__device__ __forceinline__ unsigned ld_a32(const void* p) {
  return __hip_atomic_load((const unsigned*)p, __ATOMIC_RELAXED, __HIP_MEMORY_SCOPE_AGENT);
}
__device__ __forceinline__ unsigned long long ld_a64(const void* p) {
  return __hip_atomic_load((const unsigned long long*)p, __ATOMIC_RELAXED, __HIP_MEMORY_SCOPE_AGENT);
}
__device__ __forceinline__ void st_a32(void* p, unsigned v) {
  __hip_atomic_store((unsigned*)p, v, __ATOMIC_RELAXED, __HIP_MEMORY_SCOPE_AGENT);
}
__device__ __forceinline__ void st_a64(void* p, unsigned long long v) {
  __hip_atomic_store((unsigned long long*)p, v, __ATOMIC_RELAXED, __HIP_MEMORY_SCOPE_AGENT);
}
__device__ __forceinline__ float lo_f(unsigned long long u) {
  return __builtin_bit_cast(float, (unsigned)(u & 0xffffffffu));
}
__device__ __forceinline__ float hi_f(unsigned long long u) {
  return __builtin_bit_cast(float, (unsigned)(u >> 32));
}
__device__ __forceinline__ unsigned long long pack_f2(float a, float b) {
  return (unsigned long long)__builtin_bit_cast(unsigned, a)
       | ((unsigned long long)__builtin_bit_cast(unsigned, b) << 32);
}
__device__ __forceinline__ float2 bf2f(unsigned u) {
  float2 r;
  unsigned lo = u << 16, hi = u & 0xffff0000u;
  r.x = __builtin_bit_cast(float, lo);
  r.y = __builtin_bit_cast(float, hi);
  return r;
}
__device__ __forceinline__ unsigned pack_bf2(float a, float b) {
  __bf16 ba = (__bf16)a, bb = (__bf16)b;
  unsigned short ua = __builtin_bit_cast(unsigned short, ba);
  unsigned short ub = __builtin_bit_cast(unsigned short, bb);
  return (unsigned)ua | ((unsigned)ub << 16);
}
__device__ __forceinline__ bf16x8 cvt8(float4 lo, float4 hi) {
  bf16x8 v;
  v[0]=(__bf16)lo.x; v[1]=(__bf16)lo.y; v[2]=(__bf16)lo.z; v[3]=(__bf16)lo.w;
  v[4]=(__bf16)hi.x; v[5]=(__bf16)hi.y; v[6]=(__bf16)hi.z; v[7]=(__bf16)hi.w;
  return v;
}
__device__ __forceinline__ float fsig(float x) {
  return __builtin_amdgcn_rcpf(1.f + __expf(-x));
}
__device__ __forceinline__ float ftanh(float x) {
  float e = __expf(-2.f * fabsf(x));
  float t = (1.f - e) * __builtin_amdgcn_rcpf(1.f + e);
  return __builtin_copysignf(t, x);
}
// legacy monotonic-counter grid barrier (kept for fallback path)
__device__ __forceinline__ void gbar(unsigned* cnt, int target) {
  __syncthreads();
  if (threadIdx.x == 0) {
    __hip_atomic_fetch_add(cnt, 1u, __ATOMIC_RELAXED, __HIP_MEMORY_SCOPE_AGENT);
    while ((int)__hip_atomic_load(cnt, __ATOMIC_RELAXED, __HIP_MEMORY_SCOPE_AGENT) < target) {
      __builtin_amdgcn_s_sleep(1);
    }
  }
  __syncthreads();
}
// broadcast barrier for the 64 consumer blocks: per-block flag line, wave-0
// parallel poll. Also publishes the phase to `rel` for the producers.
__device__ __forceinline__ void cbar(unsigned* flags, unsigned* rel, int myb, int phase) {
  __syncthreads();   // drains vmcnt -> this block's atomic stores are at MALL
  if (threadIdx.x < 64) {
    if (threadIdx.x == 0)
      st_a32(flags + (size_t)myb * 16, (unsigned)phase);
    const unsigned* fp = flags + (size_t)threadIdx.x * 16;
    for (;;) {
      int v = (int)ld_a32(fp);
      if (__all(v >= phase)) break;
      __builtin_amdgcn_s_sleep(2);
    }
    if (myb == 0 && threadIdx.x == 0)
      st_a32(rel, (unsigned)phase);
  }
  __syncthreads();
}

// swizzled LDS address for the producer tiles ([64] rows x 1024B, XOR bank swz)
#define LDS_AT(base, row, kb) ((base) + (size_t)(row)*1024 + ((kb) ^ (((row) & 7) << 4)))

// ======================= shared prep kernels ================================
__global__ __launch_bounds__(256) void h_init(
    const float* __restrict__ h0, float* __restrict__ h, bf16_t* __restrict__ hbf)
{
  int idx = blockIdx.x * 256 + threadIdx.x;   // 16384
  float v = h0[idx & 511];
  h[idx] = v;
  hbf[idx] = (__bf16)v;
}

__global__ __launch_bounds__(256) void lengths_kernel(
    const int* __restrict__ cpt, int* __restrict__ len)
{
  int r = blockIdx.x * 256 + threadIdx.x;
  if (r < 1536) {
    int c = 0;
    for (int s = 0; s < 64; ++s) c += (cpt[r*64 + s] != 0);
    len[r] = c > 1 ? c : 1;
  }
}

// ======================= v4 prep ============================================
__global__ __launch_bounds__(256) void prep_v4(
    const float* __restrict__ Weh, const float* __restrict__ Win,
    const float* __restrict__ Wout, const float* __restrict__ Whh,
    const float* __restrict__ Wih,
    bf16_t* __restrict__ WehB, bf16_t* __restrict__ W2,
    bf16_t* __restrict__ WH, bf16_t* __restrict__ WI)
{
  int idx = blockIdx.x * 256 + threadIdx.x;   // 2,621,440 total
  if (idx < 262144) {
    WehB[idx] = (__bf16)Weh[idx];
  } else if (idx < 786432) {
    int t = idx - 262144;
    int r = t >> 9, d = t & 511;
    float v = (r < 512) ? Win[(size_t)d*512 + r] : Wout[(size_t)(r-512)*1024 + d];
    W2[t] = (__bf16)v;
  } else if (idx < 1835008) {
    int t = idx - 786432;
    int r = t >> 9, d = t & 511;
    float v = (r < 1536) ? Whh[(size_t)r*512 + d] : Wout[(size_t)(r-1536)*1024 + 512 + d];
    WH[t] = (__bf16)v;
  } else if (idx < 2621440) {
    int t = idx - 1835008;
    WI[t] = (__bf16)Wih[t];
  }
}

// ======================= v4 persistent kernel ===============================
// blocks 0..31  : attention consumer for batch g (scores = h.P, softmax,
//                 xc = sum align * Qt)
// blocks 32..63 : hW GEMM consumer (gh rows / hW2 rows of WH)
// blocks 64..255: producers: chunk (i,g) -> A1 = bf16(table[tok]) ->
//                 Mem = elu(A1@Weh^T + beh) -> P,Qt = Mem@W2 rows -> ring
__global__ __launch_bounds__(256) void fused_scan(
    const int* __restrict__ cpt, const float* __restrict__ table,
    const float* __restrict__ beh, const int* __restrict__ lengths,
    const bf16_t* __restrict__ WehB, const bf16_t* __restrict__ W2,
    const bf16_t* __restrict__ WH, const bf16_t* __restrict__ WI,
    const float* __restrict__ b_ih, const float* __restrict__ b_hh,
    bf16_t* __restrict__ ring,
    float* __restrict__ gh, float* __restrict__ hW2, float* __restrict__ xc,
    float* __restrict__ h, bf16_t* __restrict__ hbf,
    unsigned* __restrict__ flags, unsigned* __restrict__ rel,
    unsigned* __restrict__ pd, float* __restrict__ out)
{
  // 128 KiB LDS -> exactly 1 block/CU; 256 blocks = 256 CUs, all co-resident.
  __shared__ __align__(16) unsigned char smem[131072];

  const int tid = threadIdx.x, lane = tid & 63, w = tid >> 6;
  const int quad = lane >> 4, l15 = lane & 15;

  if (blockIdx.x >= 64) {
    // =========================== PRODUCER ==================================
    unsigned char* A1 = smem;            // [64]x1024B swizzled, bf16 emb rows
    unsigned char* ME = smem + 65536;    // [64]x1024B swizzled, bf16 mem rows
    const int pid = blockIdx.x - 64;     // 0..191
    for (int c = pid; c < 1536; c += 192) {
      const int i = c >> 5, g = c & 31;
      // ring-slot guard: slot (i%RW) reusable once att blocks passed phase 1
      // of step i-RW (rel >= 2*(i-RW)+1).
      if (i >= RW) {
        const int need = 2*(i - RW) + 1;
        if (tid == 0) {
          while ((int)ld_a32(rel) < need) __builtin_amdgcn_s_sleep(4);
        }
        __syncthreads();
      }
      // ---- stage A1 = bf16(table[tok_s]) for sentence i of batch g ----
      {
        const int nrow = g*48 + i;               // concept row
        const int s = tid >> 2, q = tid & 3;
        const int tok = cpt[nrow*64 + s];
        const float* tr = table + (size_t)tok*512 + q*128;
        #pragma unroll
        for (int it = 0; it < 16; ++it) {
          float4 lo = *(const float4*)(tr + it*8);
          float4 hi = *(const float4*)(tr + it*8 + 4);
          const int kb = q*256 + it*16;
          *(bf16x8*)LDS_AT(A1, s, kb) = cvt8(lo, hi);
        }
      }
      __syncthreads();
      // ---- GEMM1: ME = bf16(elu(A1 @ WehB-rows + beh)) ----
      for (int nb = 0; nb < 8; ++nb) {
        const int n0 = w*128 + nb*16;
        const bf16_t* brow = WehB + (size_t)(n0 + l15)*512;
        f32x4 ac0={0,0,0,0}, ac1={0,0,0,0}, ac2={0,0,0,0}, ac3={0,0,0,0};
        #pragma unroll
        for (int kt = 0; kt < 16; ++kt) {
          const int k = kt*32 + quad*8, k2 = k*2;
          bf16x8 bfr = *(const bf16x8*)(brow + k);
          bf16x8 x0 = *(const bf16x8*)LDS_AT(A1, l15,      k2);
          bf16x8 x1 = *(const bf16x8*)LDS_AT(A1, 16 + l15, k2);
          bf16x8 x2 = *(const bf16x8*)LDS_AT(A1, 32 + l15, k2);
          bf16x8 x3 = *(const bf16x8*)LDS_AT(A1, 48 + l15, k2);
          ac0 = MFMA16(x0, bfr, ac0);
          ac1 = MFMA16(x1, bfr, ac1);
          ac2 = MFMA16(x2, bfr, ac2);
          ac3 = MFMA16(x3, bfr, ac3);
        }
        const float bias = beh[n0 + l15];
        f32x4 av[4] = {ac0, ac1, ac2, ac3};
        #pragma unroll
        for (int mt = 0; mt < 4; ++mt) {
          #pragma unroll
          for (int r = 0; r < 4; ++r) {
            const int m = mt*16 + quad*4 + r;
            float v = av[mt][r] + bias;
            v = v > 0.f ? v : expm1f(v);
            float v2 = __shfl_xor(v, 1);           // neighbor column
            if ((l15 & 1) == 0) {
              const int kb = (n0 + l15)*2;
              *(unsigned*)LDS_AT(ME, m, kb) = pack_bf2(v, v2);
            }
          }
        }
      }
      __syncthreads();
      // ---- GEMM2: ring chunk = ME @ W2-rows (P plain, Q transposed) ----
      {
        bf16_t* rc = ring + ((size_t)((i % RW)*32 + g))*65536;
        for (int nb = 0; nb < 16; ++nb) {
          const int n0 = w*256 + nb*16;            // 0..1023
          const bf16_t* brow = W2 + (size_t)(n0 + l15)*512;
          f32x4 ac0={0,0,0,0}, ac1={0,0,0,0}, ac2={0,0,0,0}, ac3={0,0,0,0};
          #pragma unroll
          for (int kt = 0; kt < 16; ++kt) {
            const int k = kt*32 + quad*8, k2 = k*2;
            bf16x8 bfr = *(const bf16x8*)(brow + k);
            bf16x8 x0 = *(const bf16x8*)LDS_AT(ME, l15,      k2);
            bf16x8 x1 = *(const bf16x8*)LDS_AT(ME, 16 + l15, k2);
            bf16x8 x2 = *(const bf16x8*)LDS_AT(ME, 32 + l15, k2);
            bf16x8 x3 = *(const bf16x8*)LDS_AT(ME, 48 + l15, k2);
            ac0 = MFMA16(x0, bfr, ac0);
            ac1 = MFMA16(x1, bfr, ac1);
            ac2 = MFMA16(x2, bfr, ac2);
            ac3 = MFMA16(x3, bfr, ac3);
          }
          f32x4 av[4] = {ac0, ac1, ac2, ac3};
          if (w < 2) {
            // P rows: [s][512]
            #pragma unroll
            for (int mt = 0; mt < 4; ++mt) {
              #pragma unroll
              for (int r = 0; r < 4; ++r) {
                const int m = mt*16 + quad*4 + r;
                float v = av[mt][r];
                float v2 = __shfl_xor(v, 1);
                if ((l15 & 1) == 0)
                  st_a32(rc + (size_t)m*512 + n0 + l15, pack_bf2(v, v2));
              }
            }
          } else {
            // Qt rows: [d][64], pack adjacent s (same lane: r, r+1)
            const int d = n0 + l15 - 512;
            #pragma unroll
            for (int mt = 0; mt < 4; ++mt) {
              #pragma unroll
              for (int r = 0; r < 4; r += 2) {
                const int m0 = mt*16 + quad*4 + r;
                st_a32(rc + 32768 + (size_t)d*64 + m0,
                       pack_bf2(av[mt][r], av[mt][r+1]));
              }
            }
          }
        }
      }
      __syncthreads();   // drain stores before publishing
      if (tid == 0)
        __hip_atomic_store(pd + c, 1u, __ATOMIC_RELEASE, __HIP_MEMORY_SCOPE_AGENT);
    }
    return;
  }

  // ============================= CONSUMER ==================================
  unsigned short* x_lds = (unsigned short*)smem;          // 32 rows x 1040B
  float* hsm    = (float*)(smem + 33280);                 // 512 f32
  float* sc_lds = (float*)(smem + 35328);                 // 64
  float* al_lds = (float*)(smem + 35584);                 // 64
  float* gi_lds = (float*)(smem + 35840);                 // 24*33 f32

  const int g = blockIdx.x;
  int phase = 0;

  for (int i = 0; i < 48; ++i) {
    // =========================== phase 1 ===================================
    if (g < 32) {
      // ---- attention for batch g (reads ring chunk (i,g)) ----
      if (tid == 0) {
        while (ld_a32(pd + (i*32 + g)) == 0u) __builtin_amdgcn_s_sleep(2);
      }
      { int t2 = tid * 2;
        unsigned long long v = ld_a64(h + g*512 + t2);
        hsm[t2] = lo_f(v); hsm[t2+1] = hi_f(v); }
      __syncthreads();
      const bf16_t* ringc = ring + ((size_t)((i % RW)*32 + g))*65536;
      {
        const int s = tid >> 2, p = tid & 3;
        const bf16_t* prow = ringc + (size_t)s*512 + p*128;
        const float* qp = hsm + p*128;
        float sum = 0.f;
        #pragma unroll
        for (int it = 0; it < 32; ++it) {
          unsigned long long u = ld_a64(prow + it*4);
          float2 f0 = bf2f((unsigned)u), f1 = bf2f((unsigned)(u >> 32));
          const float* qq = qp + it*4;
          sum += f0.x*qq[0] + f0.y*qq[1] + f1.x*qq[2] + f1.y*qq[3];
        }
        sum += __shfl_xor(sum, 1);
        sum += __shfl_xor(sum, 2);
        if (p == 0) {
          int len = lengths[g*48 + i];
          sc_lds[s] = (s < len) ? sum : -1e30f;
        }
      }
      __syncthreads();
      if (tid < 64) {
        float v = sc_lds[tid];
        float mx = v;
        #pragma unroll
        for (int o = 32; o; o >>= 1) mx = fmaxf(mx, __shfl_xor(mx, o));
        float e = __expf(v - mx);
        float sm = e;
        #pragma unroll
        for (int o = 32; o; o >>= 1) sm += __shfl_xor(sm, o);
        al_lds[tid] = e * __builtin_amdgcn_rcpf(sm);
      }
      __syncthreads();
      {
        const int d0 = tid * 2;
        const bf16_t* q0 = ringc + 32768 + (size_t)d0*64;
        float c0 = 0.f, c1 = 0.f;
        #pragma unroll
        for (int it = 0; it < 16; ++it) {
          unsigned long long ua = ld_a64(q0 + it*4);        // Qt[d0][s..s+3]
          unsigned long long ub = ld_a64(q0 + 64 + it*4);   // Qt[d0+1][..]
          float2 a0 = bf2f((unsigned)ua), a1 = bf2f((unsigned)(ua >> 32));
          float2 b0 = bf2f((unsigned)ub), b1 = bf2f((unsigned)(ub >> 32));
          const int s4 = it*4;
          float w0 = al_lds[s4], w1 = al_lds[s4+1], w2 = al_lds[s4+2], w3 = al_lds[s4+3];
          c0 += w0*a0.x + w1*a0.y + w2*a1.x + w3*a1.y;
          c1 += w0*b0.x + w1*b0.y + w2*b1.x + w3*b1.y;
        }
        st_a64(xc + g*512 + d0, pack_f2(c0, c1));
      }
    } else {
      // ---- hW GEMM: rows R0..R0+63 of WH = [Whh ; Wh2] ----
      const int R0 = 64 * (g - 32);
      for (int it = 0; it < 16; ++it) {
        int c = tid + 256*it;
        int row = c >> 7, cc = c & 127;
        unsigned long long v = ld_a64(hbf + row*512 + cc*4);
        *(unsigned long long*)((char*)x_lds + row*1040 + cc*8) = v;
      }
      __syncthreads();
      f32x4 acc[8];
      #pragma unroll
      for (int t = 0; t < 8; ++t) acc[t] = (f32x4){0,0,0,0};
      #pragma unroll
      for (int kt = 0; kt < 16; ++kt) {
        const int k = kt*32 + quad*8;
        bf16x8 a0 = *(const bf16x8*)((char*)x_lds + l15*1040 + k*2);
        bf16x8 a1 = *(const bf16x8*)((char*)x_lds + (16 + l15)*1040 + k*2);
        #pragma unroll
        for (int nt = 0; nt < 4; ++nt) {
          bf16x8 bfr = *(const bf16x8*)(WH + (size_t)(R0 + nt*16 + l15)*512 + k);
          acc[nt]   = MFMA16(a0, bfr, acc[nt]);
          acc[4+nt] = MFMA16(a1, bfr, acc[4+nt]);
        }
      }
      #pragma unroll
      for (int nt = 0; nt < 4; ++nt) {
        const int R = R0 + nt*16 + l15;
        const float bias = (R < 1536) ? b_hh[R] : 0.f;
        #pragma unroll
        for (int mt = 0; mt < 2; ++mt) {
          #pragma unroll
          for (int r = 0; r < 4; ++r) {
            int b = 16*mt + quad*4 + r;
            float v = acc[mt*4 + nt][r] + bias;
            if (R < 1536) st_a32(gh + b*1536 + R, __builtin_bit_cast(unsigned, v));
            else          st_a32(hW2 + b*512 + (R - 1536), __builtin_bit_cast(unsigned, v));
          }
        }
      }
    }
    cbar(flags, rel, g, ++phase);

    // =========================== phase 2 ===================================
    // x = tanh(xc + hW2) -> x_lds (bf16, padded rows); duplicated per block.
    for (int it = 0; it < 32; ++it) {
      int c2 = tid + 256*it;            // 8192 pairs
      int b = c2 >> 8, dp = c2 & 255, d0v = dp*2;
      unsigned long long xv = ld_a64(xc + b*512 + d0v);
      unsigned long long hv = ld_a64(hW2 + b*512 + d0v);
      float t0 = ftanh(lo_f(xv) + lo_f(hv));
      float t1 = ftanh(hi_f(xv) + hi_f(hv));
      *(unsigned*)((char*)x_lds + b*1040 + d0v*2) = pack_bf2(t0, t1);
    }
    __syncthreads();
    {
      // gi slice: local rows 0..23 = W_ih rows {d, 512+d, 1024+d : d in 8g..8g+7}
      f32x4 ga0={0,0,0,0}, ga1={0,0,0,0}, ga2={0,0,0,0}, ga3={0,0,0,0};
      const int lr0 = l15, lr1c = (16 + l15 < 24) ? (16 + l15) : 23;
      const bf16_t* w0p = WI + ((size_t)((lr0 >> 3)*512 + 8*g + (lr0 & 7)))*512;
      const bf16_t* w1p = WI + ((size_t)((lr1c >> 3)*512 + 8*g + (lr1c & 7)))*512;
      #pragma unroll
      for (int kt = 0; kt < 16; ++kt) {
        const int k = kt*32 + quad*8;
        bf16x8 a0 = *(const bf16x8*)((char*)x_lds + l15*1040 + k*2);
        bf16x8 a1 = *(const bf16x8*)((char*)x_lds + (16 + l15)*1040 + k*2);
        bf16x8 b0 = *(const bf16x8*)(w0p + k);
        bf16x8 b1 = *(const bf16x8*)(w1p + k);
        ga0 = MFMA16(a0, b0, ga0);
        ga1 = MFMA16(a0, b1, ga1);
        ga2 = MFMA16(a1, b0, ga2);
        ga3 = MFMA16(a1, b1, ga3);
      }
      f32x4 gv[4] = {ga0, ga1, ga2, ga3};
      #pragma unroll
      for (int nt = 0; nt < 2; ++nt) {
        int lr = nt*16 + l15;
        if (lr < 24) {
          #pragma unroll
          for (int mt = 0; mt < 2; ++mt) {
            #pragma unroll
            for (int r = 0; r < 4; ++r) {
              int b = 16*mt + quad*4 + r;
              gi_lds[lr*33 + b] = gv[mt*2 + nt][r];
            }
          }
        }
      }
    }
    __syncthreads();
    {
      const int b = tid >> 3, dl = tid & 7;
      const int D = 8*g + dl;
      float ir = gi_lds[dl*33 + b]        + b_ih[D];
      float iz = gi_lds[(8+dl)*33 + b]    + b_ih[512 + D];
      float in = gi_lds[(16+dl)*33 + b]   + b_ih[1024 + D];
      float hr = __builtin_bit_cast(float, ld_a32(gh + b*1536 + D));
      float hz = __builtin_bit_cast(float, ld_a32(gh + b*1536 + 512 + D));
      float hn = __builtin_bit_cast(float, ld_a32(gh + b*1536 + 1024 + D));
      float ho = __builtin_bit_cast(float, ld_a32(h + b*512 + D));
      float rr = fsig(ir + hr);
      float zz = fsig(iz + hz);
      float nn = ftanh(in + rr * hn);
      float res = (1.f - zz) * nn + zz * ho;
      if (i == 47) {
        out[b*512 + D] = res;
      } else {
        st_a32(h + b*512 + D, __builtin_bit_cast(unsigned, res));
        float o2 = __shfl_xor(res, 1);
        if ((dl & 1) == 0) st_a32(hbf + b*512 + D, pack_bf2(res, o2));
      }
    }
    if (i == 47) break;               // no final barrier needed
    cbar(flags, rel, g, ++phase);
  }
}

// ======================= LEGACY PATH (fallback) =============================
__global__ __launch_bounds__(256) void prep_legacy(
    const float* __restrict__ Win, const float* __restrict__ Whh,
    const float* __restrict__ Wout, const float* __restrict__ Wih,
    bf16_t* __restrict__ WA, bf16_t* __restrict__ WoutB, bf16_t* __restrict__ WihB)
{
  int idx = blockIdx.x * 256 + threadIdx.x;
  if (idx < 262144)        WA[idx]            = (__bf16)Win[idx];
  else if (idx < 1048576)  WA[idx]            = (__bf16)Whh[idx - 262144];
  else if (idx < 1572864)  WoutB[idx-1048576] = (__bf16)Wout[idx - 1048576];
  else if (idx < 2359296)  WihB[idx-1572864]  = (__bf16)Wih[idx - 1572864];
}

// ---- embed GEMM: mem = bf16(elu(emb_table[cpt] @ W_eh^T + b_eh)) (legacy) ----
__global__ __launch_bounds__(256) void embed_gemm(
    const int* __restrict__ cpt, const float* __restrict__ table,
    const float* __restrict__ Weh, const float* __restrict__ beh,
    bf16_t* __restrict__ mem)
{
  __shared__ unsigned short A_lds[64][40];
  __shared__ unsigned short B_lds[64][40];
  const int bid = blockIdx.x;
  const int M0 = (bid >> 3) * 64;
  const int N0 = (bid & 7) * 64;
  const int tid = threadIdx.x, lane = tid & 63, w = tid >> 6;
  const int l15 = lane & 15, quad = lane >> 4;
  const int srow = tid >> 2;
  const int koff = (tid & 3) * 8;
  const int tok = cpt[M0 + srow];
  const float* arow = table + (size_t)tok * 512;
  const float* brow = Weh + (size_t)(N0 + srow) * 512;

  f32x4 acc0 = {0,0,0,0}, acc1 = {0,0,0,0}, acc2 = {0,0,0,0}, acc3 = {0,0,0,0};
  for (int kt = 0; kt < 16; ++kt) {
    const int k0 = kt * 32;
    float4 alo = *(const float4*)(arow + k0 + koff);
    float4 ahi = *(const float4*)(arow + k0 + koff + 4);
    float4 blo = *(const float4*)(brow + k0 + koff);
    float4 bhi = *(const float4*)(brow + k0 + koff + 4);
    __syncthreads();
    *(bf16x8*)(&A_lds[srow][koff]) = cvt8(alo, ahi);
    *(bf16x8*)(&B_lds[srow][koff]) = cvt8(blo, bhi);
    __syncthreads();
    const int kq = quad * 8;
    bf16x8 bfr = *(const bf16x8*)(&B_lds[16*w + l15][kq]);
    bf16x8 a0 = *(const bf16x8*)(&A_lds[l15][kq]);
    bf16x8 a1 = *(const bf16x8*)(&A_lds[16 + l15][kq]);
    bf16x8 a2 = *(const bf16x8*)(&A_lds[32 + l15][kq]);
    bf16x8 a3 = *(const bf16x8*)(&A_lds[48 + l15][kq]);
    acc0 = MFMA16(a0, bfr, acc0);
    acc1 = MFMA16(a1, bfr, acc1);
    acc2 = MFMA16(a2, bfr, acc2);
    acc3 = MFMA16(a3, bfr, acc3);
  }
  const int n = N0 + 16*w + l15;
  const float bias = beh[n];
  f32x4 accs[4] = {acc0, acc1, acc2, acc3};
  #pragma unroll
  for (int mt = 0; mt < 4; ++mt) {
    #pragma unroll
    for (int r = 0; r < 4; ++r) {
      int m = M0 + mt*16 + quad*4 + r;
      float v = accs[mt][r] + bias;
      v = v > 0.f ? v : expm1f(v);
      int s = m & 63, nrow = m >> 6;
      int sent = nrow % 48, b = nrow / 48;
      mem[(((size_t)(sent*32 + b))*64 + s)*512 + n] = (__bf16)v;
    }
  }
}

__global__ __launch_bounds__(256) void scan_legacy(
    const bf16_t* __restrict__ mem, const int* __restrict__ lengths,
    const bf16_t* __restrict__ WA, const bf16_t* __restrict__ Wout, const bf16_t* __restrict__ Wih,
    const float* __restrict__ b_ih, const float* __restrict__ b_hh,
    float* __restrict__ q, float* __restrict__ gh,
    float* __restrict__ h, bf16_t* __restrict__ hbf,
    bf16_t* __restrict__ cbf, bf16_t* __restrict__ xbf,
    unsigned* __restrict__ bar, float* __restrict__ out)
{
  __shared__ __align__(16) unsigned char smem[52352];
  unsigned short* h_lds = (unsigned short*)smem;
  unsigned short* x_lds = (unsigned short*)smem;
  float* q_lds  = (float*)(smem + 33280);
  float* sc_lds = (float*)(smem + 35328);
  float* al_lds = (float*)(smem + 35584);
  unsigned short* c_lds = (unsigned short*)(smem + 33280);
  float* xb_lds = (float*)(smem + 50176);
  float* gi_lds = (float*)(smem + 33280);

  const int g = blockIdx.x, tid = threadIdx.x, lane = tid & 63, w = tid >> 6;
  const int quad = lane >> 4, l15 = lane & 15;
  int phase = 0;

  for (int i = 0; i < 48; ++i) {
    for (int it = 0; it < 16; ++it) {
      int chunk = tid + 256*it;
      int row = chunk >> 7, cc = chunk & 127;
      unsigned long long v = ld_a64(hbf + row*512 + cc*4);
      *(unsigned long long*)((char*)h_lds + row*1040 + cc*8) = v;
    }
    __syncthreads();
    {
      f32x4 acc0 = {0,0,0,0}, acc1 = {0,0,0,0};
      const int nrow = 64*g + 16*w + l15;
      const bf16_t* wrow = WA + (size_t)nrow * 512;
      #pragma unroll
      for (int kt = 0; kt < 16; ++kt) {
        const int k = kt*32 + quad*8;
        bf16x8 bfr = *(const bf16x8*)(wrow + k);
        bf16x8 a0 = *(const bf16x8*)((char*)h_lds + l15*1040 + k*2);
        bf16x8 a1 = *(const bf16x8*)((char*)h_lds + (16 + l15)*1040 + k*2);
        acc0 = MFMA16(a0, bfr, acc0);
        acc1 = MFMA16(a1, bfr, acc1);
      }
      const float bias = (nrow >= 512) ? b_hh[nrow - 512] : 0.f;
      #pragma unroll
      for (int r = 0; r < 4; ++r) {
        int b0 = quad*4 + r;
        float v0 = acc0[r] + bias, v1 = acc1[r] + bias;
        if (nrow < 512) {
          st_a32(q + b0*512 + nrow,        __builtin_bit_cast(unsigned, v0));
          st_a32(q + (b0+16)*512 + nrow,   __builtin_bit_cast(unsigned, v1));
        } else {
          st_a32(gh + b0*1536 + nrow-512,      __builtin_bit_cast(unsigned, v0));
          st_a32(gh + (b0+16)*1536 + nrow-512, __builtin_bit_cast(unsigned, v1));
        }
      }
    }
    gbar(bar, ++phase * 32);
    {
      for (int it = 0; it < 2; ++it) {
        int idx = tid + 256*it;
        unsigned v = ld_a32(q + g*512 + idx);
        q_lds[idx] = __builtin_bit_cast(float, v);
      }
      __syncthreads();
      const bf16_t* mrow = mem + ((size_t)(i*32 + g)) * 64 * 512;
      {
        const int s = tid >> 2, p = tid & 3;
        const uint4* mp = (const uint4*)(mrow + s*512 + p*128);
        const float* qp = q_lds + p*128;
        float sum = 0.f;
        #pragma unroll
        for (int it = 0; it < 16; ++it) {
          uint4 u = mp[it];
          float2 f0 = bf2f(u.x), f1 = bf2f(u.y), f2 = bf2f(u.z), f3 = bf2f(u.w);
          const float* qq = qp + it*8;
          sum += f0.x*qq[0] + f0.y*qq[1] + f1.x*qq[2] + f1.y*qq[3]
               + f2.x*qq[4] + f2.y*qq[5] + f3.x*qq[6] + f3.y*qq[7];
        }
        sum += __shfl_xor(sum, 1);
        sum += __shfl_xor(sum, 2);
        if (p == 0) {
          int len = lengths[g*48 + i];
          sc_lds[s] = (s < len) ? sum : -1e30f;
        }
      }
      __syncthreads();
      if (tid < 64) {
        float v = sc_lds[tid];
        float mx = v;
        #pragma unroll
        for (int o = 32; o; o >>= 1) mx = fmaxf(mx, __shfl_xor(mx, o));
        float e = __expf(v - mx);
        float sm = e;
        #pragma unroll
        for (int o = 32; o; o >>= 1) sm += __shfl_xor(sm, o);
        al_lds[tid] = e / sm;
      }
      __syncthreads();
      {
        const int d0 = tid * 2;
        float c0 = 0.f, c1 = 0.f;
        for (int s2 = 0; s2 < 64; ++s2) {
          unsigned u = *(const unsigned*)(mrow + s2*512 + d0);
          float2 f = bf2f(u);
          float a = al_lds[s2];
          c0 += a * f.x; c1 += a * f.y;
        }
        st_a32(cbf + g*512 + d0, pack_bf2(c0, c1));
      }
    }
    gbar(bar, ++phase * 32);
    {
      f32x4 acc = {0,0,0,0};
      const int nrow = 16*g + l15;
      const bf16_t* wrow = Wout + (size_t)nrow * 1024;
      for (int kh = 0; kh < 2; ++kh) {
        for (int it = 0; it < 8; ++it) {
          int cid = tid + 256*it;
          int row = cid >> 6, cc = cid & 63;
          unsigned long long v = ld_a64(cbf + row*512 + kh*256 + cc*4);
          *(unsigned long long*)((char*)c_lds + row*528 + cc*8) = v;
        }
        __syncthreads();
        if (w < 2) {
          #pragma unroll
          for (int kt = 0; kt < 8; ++kt) {
            const int kl = kt*32 + quad*8;
            bf16x8 bfr = *(const bf16x8*)(wrow + kh*256 + kl);
            bf16x8 af  = *(const bf16x8*)((char*)c_lds + (16*w + l15)*528 + kl*2);
            acc = MFMA16(af, bfr, acc);
          }
        }
        __syncthreads();
      }
      if (w < 2) {
        #pragma unroll
        for (int kt = 0; kt < 16; ++kt) {
          const int k = kt*32 + quad*8;
          bf16x8 bfr = *(const bf16x8*)(wrow + 512 + k);
          bf16x8 af  = *(const bf16x8*)((char*)h_lds + (16*w + l15)*1040 + k*2);
          acc = MFMA16(af, bfr, acc);
        }
        #pragma unroll
        for (int r = 0; r < 4; ++r)
          xb_lds[w*272 + l15*17 + quad*4 + r] = acc[r];
      }
      __syncthreads();
      {
        const int b = tid >> 3, np = tid & 7;
        const int mt = b >> 4, ml = b & 15;
        float v0 = ftanh(xb_lds[mt*272 + (2*np)*17 + ml]);
        float v1 = ftanh(xb_lds[mt*272 + (2*np+1)*17 + ml]);
        st_a32(xbf + b*512 + 16*g + 2*np, pack_bf2(v0, v1));
      }
    }
    gbar(bar, ++phase * 32);
    {
      for (int it = 0; it < 16; ++it) {
        int chunk = tid + 256*it;
        int row = chunk >> 7, cc = chunk & 127;
        unsigned long long v = ld_a64(xbf + row*512 + cc*4);
        *(unsigned long long*)((char*)x_lds + row*1040 + cc*8) = v;
      }
      __syncthreads();
      #pragma unroll
      for (int tt = 0; tt < 2; ++tt) {
        const int t = w + 4*tt;
        if (t < 6) {
          const int nt = t % 3, mt = t / 3;
          f32x4 acc = {0,0,0,0};
          const int nrow = nt*512 + 16*g + l15;
          const bf16_t* wrow = Wih + (size_t)nrow * 512;
          #pragma unroll
          for (int kt = 0; kt < 16; ++kt) {
            const int k = kt*32 + quad*8;
            bf16x8 bfr = *(const bf16x8*)(wrow + k);
            bf16x8 af  = *(const bf16x8*)((char*)x_lds + (16*mt + l15)*1040 + k*2);
            acc = MFMA16(af, bfr, acc);
          }
          #pragma unroll
          for (int r = 0; r < 4; ++r)
            gi_lds[t*272 + l15*17 + quad*4 + r] = acc[r];
        }
      }
      __syncthreads();
      {
        const int b = tid >> 3, dlp = tid & 7;
        const int mt = b >> 4, ml = b & 15;
        const int d0 = 16*g + 2*dlp;
        unsigned long long ur = ld_a64(gh + b*1536 + d0);
        unsigned long long uz = ld_a64(gh + b*1536 + 512 + d0);
        unsigned long long un = ld_a64(gh + b*1536 + 1024 + d0);
        unsigned long long uh = ld_a64(h + b*512 + d0);
        float res[2];
        #pragma unroll
        for (int e = 0; e < 2; ++e) {
          int dl = 2*dlp + e;
          float ir = gi_lds[(mt*3+0)*272 + dl*17 + ml] + b_ih[16*g + dl];
          float iz = gi_lds[(mt*3+1)*272 + dl*17 + ml] + b_ih[512 + 16*g + dl];
          float in = gi_lds[(mt*3+2)*272 + dl*17 + ml] + b_ih[1024 + 16*g + dl];
          float hr = e ? hi_f(ur) : lo_f(ur);
          float hz = e ? hi_f(uz) : lo_f(uz);
          float hn = e ? hi_f(un) : lo_f(un);
          float ho = e ? hi_f(uh) : lo_f(uh);
          float rr = fsig(ir + hr);
          float zz = fsig(iz + hz);
          float nn = ftanh(in + rr * hn);
          res[e] = (1.f - zz) * nn + zz * ho;
        }
        if (i == 47) {
          out[b*512 + d0]     = res[0];
          out[b*512 + d0 + 1] = res[1];
        } else {
          st_a64(h + b*512 + d0, pack_f2(res[0], res[1]));
          st_a32(hbf + b*512 + d0, pack_bf2(res[0], res[1]));
        }
      }
    }
    gbar(bar, ++phase * 32);
  }
}

// ---------------------------------------------------------------------------
extern "C" void kernel_launch(void* const* d_in, const int* in_sizes, int n_in,
                              void* d_out, int out_size, void* d_ws, size_t ws_size,
                              hipStream_t stream) {
  const int*   cpt   = (const int*)d_in[0];
  const float* table = (const float*)d_in[2];
  const float* Weh   = (const float*)d_in[3];
  const float* beh   = (const float*)d_in[4];
  const float* h0    = (const float*)d_in[5];
  const float* Win   = (const float*)d_in[6];
  const float* Wout  = (const float*)d_in[7];
  const float* Wih   = (const float*)d_in[8];
  const float* Whh   = (const float*)d_in[9];
  const float* bih   = (const float*)d_in[10];
  const float* bhh   = (const float*)d_in[11];
  char* ws = (char*)d_ws;

  if (ws_size >= WS_V4) {
    bf16_t* ring = (bf16_t*)(ws + V_RING);
    bf16_t* WehB = (bf16_t*)(ws + V_WEH);
    bf16_t* W2   = (bf16_t*)(ws + V_W2);
    bf16_t* WH   = (bf16_t*)(ws + V_WH);
    bf16_t* WI   = (bf16_t*)(ws + V_WI);
    int*    len  = (int*)(ws + V_LEN);
    float*  h    = (float*)(ws + V_H);
    bf16_t* hbf  = (bf16_t*)(ws + V_HBF);
    float*  gh   = (float*)(ws + V_GH);
    float*  hW2  = (float*)(ws + V_HW2);
    float*  xc   = (float*)(ws + V_XC);
    unsigned* flags = (unsigned*)(ws + V_FLG);
    unsigned* rel   = (unsigned*)(ws + V_REL);
    unsigned* pd    = (unsigned*)(ws + V_PD);

    hipMemsetAsync(ws + V_FLG, 0, 4096 + 64 + 6144, stream);
    prep_v4<<<10240, 256, 0, stream>>>(Weh, Win, Wout, Whh, Wih, WehB, W2, WH, WI);
    h_init<<<64, 256, 0, stream>>>(h0, h, hbf);
    lengths_kernel<<<6, 256, 0, stream>>>(cpt, len);
    fused_scan<<<256, 256, 0, stream>>>(cpt, table, beh, len,
                                        WehB, W2, WH, WI, bih, bhh,
                                        ring, gh, hW2, xc, h, hbf,
                                        flags, rel, pd, (float*)d_out);
  } else if (ws_size >= WS_LEG) {
    bf16_t* mem   = (bf16_t*)(ws + L_MEM);
    bf16_t* WA    = (bf16_t*)(ws + L_WA);
    bf16_t* WoutB = (bf16_t*)(ws + L_WOUT);
    bf16_t* WihB  = (bf16_t*)(ws + L_WIH);
    int*    len   = (int*)(ws + L_LEN);
    float*  h     = (float*)(ws + L_H);
    bf16_t* hbf   = (bf16_t*)(ws + L_HBF);
    float*  q     = (float*)(ws + L_Q);
    float*  gh    = (float*)(ws + L_GH);
    bf16_t* cbf   = (bf16_t*)(ws + L_CBF);
    bf16_t* xbf   = (bf16_t*)(ws + L_XBF);
    unsigned* bar = (unsigned*)(ws + L_BAR);

    hipMemsetAsync(bar, 0, 256, stream);
    prep_legacy<<<9216, 256, 0, stream>>>(Win, Whh, Wout, Wih, WA, WoutB, WihB);
    h_init<<<64, 256, 0, stream>>>(h0, h, hbf);
    lengths_kernel<<<6, 256, 0, stream>>>(cpt, len);
    embed_gemm<<<12288, 256, 0, stream>>>(cpt, table, Weh, beh, mem);
    scan_legacy<<<32, 256, 0, stream>>>(mem, len, WA, WoutB, WihB, bih, bhh,
                                        q, gh, h, hbf, cbf, xbf, bar, (float*)d_out);
  }
}

// Round 3
// 1333.212 us; speedup vs baseline: 1.5097x; 1.2882x over previous
//
#include <hip/hip_runtime.h>
#include <hip/hip_bf16.h>
#include <stdint.h>

// ---------------------------------------------------------------------------
// GraphEncoder. Round 6: race fix for round 5's inline-asm coherent loads.
//  Root cause of tripwire failure: inline-asm global_load/store_dwordx4 are
//  invisible to compiler waitcnt insertion --
//   (a) attention's Qt prefetch registers were consumed with NO vmcnt wait;
//   (b) hW-GEMM's st16 stores were not drained before the cbar flag store
//       (__syncthreads only drains compiler-known vmem ops).
//  Fix: explicit s_waitcnt vmcnt(0)+sched_barrier(0) at cbar entry and before
//  Qt consumption. Structure unchanged from round 5:
//  - Phase 2 re-tiled (4-batch x 64-dim patches), GRU state in register.
//  - hW GEMM re-tiled (8-batch x 256-row tiles).
//  - 16B coherent loads/stores; Qt prefetched under score+softmax (vmcnt(16)).
//  - ght/hW2t/xct transposed [dim][batch32] for 16B stores/loads.
// ---------------------------------------------------------------------------

typedef __bf16 bf16_t;
typedef __bf16 bf16x8 __attribute__((ext_vector_type(8)));
typedef float  f32x4  __attribute__((ext_vector_type(4)));
typedef unsigned u32x4 __attribute__((ext_vector_type(4)));

#define MFMA16(a,b,c) __builtin_amdgcn_mfma_f32_16x16x32_bf16((a),(b),(c),0,0,0)

// ======================= v5 (ring) workspace ================================
static constexpr int    RW     = 12;                      // ring depth (steps)
static constexpr size_t V_RING = 0;
static constexpr size_t V_WEH  = V_RING + (size_t)RW*32*65536*2;  // 50,331,648
static constexpr size_t V_W2   = V_WEH + 524288;   // bf16 [1024][512]: Win^T ; Wc
static constexpr size_t V_WH   = V_W2  + 1048576;  // bf16 [2048][512]: Whh ; Wh2
static constexpr size_t V_WI   = V_WH  + 2097152;  // bf16 [1536][512]
static constexpr size_t V_LEN  = V_WI  + 1572864;  // int [1536]
static constexpr size_t V_H    = V_LEN + 8192;     // f32 [32][512]
static constexpr size_t V_HBF  = V_H   + 65536;    // bf16 [32][512]
static constexpr size_t V_GH   = V_HBF + 32768;    // f32 ght [1536][32]
static constexpr size_t V_HW2  = V_GH  + 196608;   // f32 hW2t [512][32]
static constexpr size_t V_XC   = V_HW2 + 65536;    // f32 xct [512][32]
static constexpr size_t V_FLG  = V_XC  + 65536;    // u32[64] consumer flags
static constexpr size_t V_REL  = V_FLG + 4096;     // u32 release counter
static constexpr size_t V_PD   = V_REL + 64;       // u32[1536] chunk-done flags
static constexpr size_t WS_V4  = V_PD  + 6144;     // ~56.0 MB

// ======================= legacy workspace layout ============================
static constexpr size_t L_MEM   = 0;
static constexpr size_t L_WA    = 100663296;
static constexpr size_t L_WOUT  = L_WA + 2097152;
static constexpr size_t L_WIH   = L_WOUT + 1048576;
static constexpr size_t L_LEN   = L_WIH + 1572864;
static constexpr size_t L_H     = L_LEN + 8192;
static constexpr size_t L_HBF   = L_H + 65536;
static constexpr size_t L_Q     = L_HBF + 32768;
static constexpr size_t L_GH    = L_Q + 65536;
static constexpr size_t L_CBF   = L_GH + 196608;
static constexpr size_t L_XBF   = L_CBF + 32768;
static constexpr size_t L_BAR   = L_XBF + 32768;
static constexpr size_t WS_LEG  = L_BAR + 256;

// ---- helpers ----
__device__ __forceinline__ unsigned ld_a32(const void* p) {
  return __hip_atomic_load((const unsigned*)p, __ATOMIC_RELAXED, __HIP_MEMORY_SCOPE_AGENT);
}
__device__ __forceinline__ unsigned long long ld_a64(const void* p) {
  return __hip_atomic_load((const unsigned long long*)p, __ATOMIC_RELAXED, __HIP_MEMORY_SCOPE_AGENT);
}
__device__ __forceinline__ void st_a32(void* p, unsigned v) {
  __hip_atomic_store((unsigned*)p, v, __ATOMIC_RELAXED, __HIP_MEMORY_SCOPE_AGENT);
}
__device__ __forceinline__ void st_a64(void* p, unsigned long long v) {
  __hip_atomic_store((unsigned long long*)p, v, __ATOMIC_RELAXED, __HIP_MEMORY_SCOPE_AGENT);
}
// 16B device-coherent load/store (bypass L1/L2 like the atomic path).
// NOTE: these are invisible to compiler waitcnt insertion -- every consumer
// of the destination registers and every signal after the stores MUST be
// preceded by an explicit vm_wait*() (rule 18).
__device__ __forceinline__ void ld16u(u32x4& d, const void* p) {
  asm volatile("global_load_dwordx4 %0, %1, off sc0 sc1"
               : "=v"(d) : "v"(p) : "memory");
}
__device__ __forceinline__ void ld16f(f32x4& d, const void* p) {
  asm volatile("global_load_dwordx4 %0, %1, off sc0 sc1"
               : "=v"(d) : "v"(p) : "memory");
}
__device__ __forceinline__ void st16(void* p, f32x4 d) {
  asm volatile("global_store_dwordx4 %0, %1, off sc0 sc1"
               :: "v"(p), "v"(d) : "memory");
}
__device__ __forceinline__ void vm_wait0() {
  asm volatile("s_waitcnt vmcnt(0)" ::: "memory");
  __builtin_amdgcn_sched_barrier(0);
}
__device__ __forceinline__ void vm_wait16() {
  asm volatile("s_waitcnt vmcnt(16)" ::: "memory");
  __builtin_amdgcn_sched_barrier(0);
}
__device__ __forceinline__ float lo_f(unsigned long long u) {
  return __builtin_bit_cast(float, (unsigned)(u & 0xffffffffu));
}
__device__ __forceinline__ float hi_f(unsigned long long u) {
  return __builtin_bit_cast(float, (unsigned)(u >> 32));
}
__device__ __forceinline__ unsigned long long pack_f2(float a, float b) {
  return (unsigned long long)__builtin_bit_cast(unsigned, a)
       | ((unsigned long long)__builtin_bit_cast(unsigned, b) << 32);
}
__device__ __forceinline__ float2 bf2f(unsigned u) {
  float2 r;
  unsigned lo = u << 16, hi = u & 0xffff0000u;
  r.x = __builtin_bit_cast(float, lo);
  r.y = __builtin_bit_cast(float, hi);
  return r;
}
__device__ __forceinline__ unsigned pack_bf2(float a, float b) {
  __bf16 ba = (__bf16)a, bb = (__bf16)b;
  unsigned short ua = __builtin_bit_cast(unsigned short, ba);
  unsigned short ub = __builtin_bit_cast(unsigned short, bb);
  return (unsigned)ua | ((unsigned)ub << 16);
}
__device__ __forceinline__ bf16x8 cvt8(float4 lo, float4 hi) {
  bf16x8 v;
  v[0]=(__bf16)lo.x; v[1]=(__bf16)lo.y; v[2]=(__bf16)lo.z; v[3]=(__bf16)lo.w;
  v[4]=(__bf16)hi.x; v[5]=(__bf16)hi.y; v[6]=(__bf16)hi.z; v[7]=(__bf16)hi.w;
  return v;
}
__device__ __forceinline__ float fsig(float x) {
  return __builtin_amdgcn_rcpf(1.f + __expf(-x));
}
__device__ __forceinline__ float ftanh(float x) {
  float e = __expf(-2.f * fabsf(x));
  float t = (1.f - e) * __builtin_amdgcn_rcpf(1.f + e);
  return __builtin_copysignf(t, x);
}
// legacy monotonic-counter grid barrier (kept for fallback path)
__device__ __forceinline__ void gbar(unsigned* cnt, int target) {
  __syncthreads();
  if (threadIdx.x == 0) {
    __hip_atomic_fetch_add(cnt, 1u, __ATOMIC_RELAXED, __HIP_MEMORY_SCOPE_AGENT);
    while ((int)__hip_atomic_load(cnt, __ATOMIC_RELAXED, __HIP_MEMORY_SCOPE_AGENT) < target) {
      __builtin_amdgcn_s_sleep(1);
    }
  }
  __syncthreads();
}
// broadcast barrier for the 64 consumer blocks: 4B-stride flags, wave-0
// parallel poll. Publishes phase to `rel`. Drains inline-asm vmem FIRST
// (syncthreads only drains compiler-known ops -- the round-5 race).
__device__ __forceinline__ void cbar(unsigned* flags, unsigned* rel, int myb, int phase) {
  vm_wait0();        // drain inline-asm st16/ld16 before signaling
  __syncthreads();
  if (threadIdx.x < 64) {
    if (threadIdx.x == 0)
      st_a32(flags + myb, (unsigned)phase);
    const unsigned* fp = flags + threadIdx.x;
    for (;;) {
      int v = (int)ld_a32(fp);
      if (__all(v >= phase)) break;
      __builtin_amdgcn_s_sleep(2);
    }
    if (myb == 0 && threadIdx.x == 0)
      st_a32(rel, (unsigned)phase);
  }
  __syncthreads();
}

// swizzled LDS address for the producer tiles ([64] rows x 1024B, XOR bank swz)
#define LDS_AT(base, row, kb) ((base) + (size_t)(row)*1024 + ((kb) ^ (((row) & 7) << 4)))

// ======================= shared prep kernels ================================
__global__ __launch_bounds__(256) void h_init(
    const float* __restrict__ h0, float* __restrict__ h, bf16_t* __restrict__ hbf)
{
  int idx = blockIdx.x * 256 + threadIdx.x;   // 16384
  float v = h0[idx & 511];
  h[idx] = v;
  hbf[idx] = (__bf16)v;
}

__global__ __launch_bounds__(256) void lengths_kernel(
    const int* __restrict__ cpt, int* __restrict__ len)
{
  int r = blockIdx.x * 256 + threadIdx.x;
  if (r < 1536) {
    int c = 0;
    for (int s = 0; s < 64; ++s) c += (cpt[r*64 + s] != 0);
    len[r] = c > 1 ? c : 1;
  }
}

// ======================= v5 prep ============================================
__global__ __launch_bounds__(256) void prep_v4(
    const float* __restrict__ Weh, const float* __restrict__ Win,
    const float* __restrict__ Wout, const float* __restrict__ Whh,
    const float* __restrict__ Wih,
    bf16_t* __restrict__ WehB, bf16_t* __restrict__ W2,
    bf16_t* __restrict__ WH, bf16_t* __restrict__ WI)
{
  int idx = blockIdx.x * 256 + threadIdx.x;   // 2,621,440 total
  if (idx < 262144) {
    WehB[idx] = (__bf16)Weh[idx];
  } else if (idx < 786432) {
    int t = idx - 262144;
    int r = t >> 9, d = t & 511;
    float v = (r < 512) ? Win[(size_t)d*512 + r] : Wout[(size_t)(r-512)*1024 + d];
    W2[t] = (__bf16)v;
  } else if (idx < 1835008) {
    int t = idx - 786432;
    int r = t >> 9, d = t & 511;
    float v = (r < 1536) ? Whh[(size_t)r*512 + d] : Wout[(size_t)(r-1536)*1024 + 512 + d];
    WH[t] = (__bf16)v;
  } else if (idx < 2621440) {
    int t = idx - 1835008;
    WI[t] = (__bf16)Wih[t];
  }
}

// ======================= v5 persistent kernel ===============================
// blocks 0..31  : phase-1 attention for batch g (scores = h.P, softmax,
//                 xct[:,g] = sum align * Qt)
// blocks 32..63 : phase-1 hW GEMM: 8-batch x 256-row tile of ght/hW2t
// all 64        : phase-2: x = tanh(xc+hW2) for own 4 batches, gi slice
//                 (192 W_ih rows), GRU for own (4b x 64D) patch
// blocks 64..255: producers: embed-gather -> elu GEMM -> P/Qt ring
__global__ __launch_bounds__(256, 1) void fused_scan(
    const int* __restrict__ cpt, const float* __restrict__ table,
    const float* __restrict__ beh, const int* __restrict__ lengths,
    const bf16_t* __restrict__ WehB, const bf16_t* __restrict__ W2,
    const bf16_t* __restrict__ WH, const bf16_t* __restrict__ WI,
    const float* __restrict__ b_ih, const float* __restrict__ b_hh,
    const float* __restrict__ h0,
    bf16_t* __restrict__ ring,
    float* __restrict__ ght, float* __restrict__ hW2t, float* __restrict__ xct,
    float* __restrict__ h, bf16_t* __restrict__ hbf,
    unsigned* __restrict__ flags, unsigned* __restrict__ rel,
    unsigned* __restrict__ pd, float* __restrict__ out)
{
  // 128 KiB LDS -> exactly 1 block/CU; 256 blocks = 256 CUs, all co-resident.
  __shared__ __align__(16) unsigned char smem[131072];

  const int tid = threadIdx.x, lane = tid & 63, w = tid >> 6;
  const int quad = lane >> 4, l15 = lane & 15;

  if (blockIdx.x >= 64) {
    // =========================== PRODUCER ==================================
    unsigned char* A1 = smem;            // [64]x1024B swizzled, bf16 emb rows
    unsigned char* ME = smem + 65536;    // [64]x1024B swizzled, bf16 mem rows
    const int pid = blockIdx.x - 64;     // 0..191
    for (int c = pid; c < 1536; c += 192) {
      const int i = c >> 5, g = c & 31;
      // ring-slot guard: slot (i%RW) reusable once att blocks passed phase 1
      // of step i-RW (rel >= 2*(i-RW)+1).
      if (i >= RW) {
        const int need = 2*(i - RW) + 1;
        if (tid == 0) {
          while ((int)ld_a32(rel) < need) __builtin_amdgcn_s_sleep(4);
        }
        __syncthreads();
      }
      // ---- stage A1 = bf16(table[tok_s]) for sentence i of batch g ----
      {
        const int nrow = g*48 + i;               // concept row
        const int s = tid >> 2, q = tid & 3;
        const int tok = cpt[nrow*64 + s];
        const float* tr = table + (size_t)tok*512 + q*128;
        #pragma unroll
        for (int it = 0; it < 16; ++it) {
          float4 lo = *(const float4*)(tr + it*8);
          float4 hi = *(const float4*)(tr + it*8 + 4);
          const int kb = q*256 + it*16;
          *(bf16x8*)LDS_AT(A1, s, kb) = cvt8(lo, hi);
        }
      }
      __syncthreads();
      // ---- GEMM1: ME = bf16(elu(A1 @ WehB-rows + beh)) ----
      for (int nb = 0; nb < 8; ++nb) {
        const int n0 = w*128 + nb*16;
        const bf16_t* brow = WehB + (size_t)(n0 + l15)*512;
        f32x4 ac0={0,0,0,0}, ac1={0,0,0,0}, ac2={0,0,0,0}, ac3={0,0,0,0};
        #pragma unroll
        for (int kt = 0; kt < 16; ++kt) {
          const int k = kt*32 + quad*8, k2 = k*2;
          bf16x8 bfr = *(const bf16x8*)(brow + k);
          bf16x8 x0 = *(const bf16x8*)LDS_AT(A1, l15,      k2);
          bf16x8 x1 = *(const bf16x8*)LDS_AT(A1, 16 + l15, k2);
          bf16x8 x2 = *(const bf16x8*)LDS_AT(A1, 32 + l15, k2);
          bf16x8 x3 = *(const bf16x8*)LDS_AT(A1, 48 + l15, k2);
          ac0 = MFMA16(x0, bfr, ac0);
          ac1 = MFMA16(x1, bfr, ac1);
          ac2 = MFMA16(x2, bfr, ac2);
          ac3 = MFMA16(x3, bfr, ac3);
        }
        const float bias = beh[n0 + l15];
        f32x4 av[4] = {ac0, ac1, ac2, ac3};
        #pragma unroll
        for (int mt = 0; mt < 4; ++mt) {
          #pragma unroll
          for (int r = 0; r < 4; ++r) {
            const int m = mt*16 + quad*4 + r;
            float v = av[mt][r] + bias;
            v = v > 0.f ? v : expm1f(v);
            float v2 = __shfl_xor(v, 1);           // neighbor column
            if ((l15 & 1) == 0) {
              const int kb = (n0 + l15)*2;
              *(unsigned*)LDS_AT(ME, m, kb) = pack_bf2(v, v2);
            }
          }
        }
      }
      __syncthreads();
      // ---- GEMM2: ring chunk = ME @ W2-rows (P plain, Q transposed) ----
      {
        bf16_t* rc = ring + ((size_t)((i % RW)*32 + g))*65536;
        for (int nb = 0; nb < 16; ++nb) {
          const int n0 = w*256 + nb*16;            // 0..1023
          const bf16_t* brow = W2 + (size_t)(n0 + l15)*512;
          f32x4 ac0={0,0,0,0}, ac1={0,0,0,0}, ac2={0,0,0,0}, ac3={0,0,0,0};
          #pragma unroll
          for (int kt = 0; kt < 16; ++kt) {
            const int k = kt*32 + quad*8, k2 = k*2;
            bf16x8 bfr = *(const bf16x8*)(brow + k);
            bf16x8 x0 = *(const bf16x8*)LDS_AT(ME, l15,      k2);
            bf16x8 x1 = *(const bf16x8*)LDS_AT(ME, 16 + l15, k2);
            bf16x8 x2 = *(const bf16x8*)LDS_AT(ME, 32 + l15, k2);
            bf16x8 x3 = *(const bf16x8*)LDS_AT(ME, 48 + l15, k2);
            ac0 = MFMA16(x0, bfr, ac0);
            ac1 = MFMA16(x1, bfr, ac1);
            ac2 = MFMA16(x2, bfr, ac2);
            ac3 = MFMA16(x3, bfr, ac3);
          }
          f32x4 av[4] = {ac0, ac1, ac2, ac3};
          if (w < 2) {
            // P rows: [s][512]
            #pragma unroll
            for (int mt = 0; mt < 4; ++mt) {
              #pragma unroll
              for (int r = 0; r < 4; ++r) {
                const int m = mt*16 + quad*4 + r;
                float v = av[mt][r];
                float v2 = __shfl_xor(v, 1);
                if ((l15 & 1) == 0)
                  st_a32(rc + (size_t)m*512 + n0 + l15, pack_bf2(v, v2));
              }
            }
          } else {
            // Qt rows: [d][64], pack adjacent s (same lane: r, r+1)
            const int d = n0 + l15 - 512;
            #pragma unroll
            for (int mt = 0; mt < 4; ++mt) {
              #pragma unroll
              for (int r = 0; r < 4; r += 2) {
                const int m0 = mt*16 + quad*4 + r;
                st_a32(rc + 32768 + (size_t)d*64 + m0,
                       pack_bf2(av[mt][r], av[mt][r+1]));
              }
            }
          }
        }
      }
      __syncthreads();   // drain stores before publishing
      if (tid == 0)
        __hip_atomic_store(pd + c, 1u, __ATOMIC_RELEASE, __HIP_MEMORY_SCOPE_AGENT);
    }
    return;
  }

  // ============================= CONSUMER ==================================
  unsigned short* x_lds = (unsigned short*)smem;          // 16 rows x 1040B
  float* hsm    = (float*)(smem + 16640);                 // 512 f32
  float* sc_lds = (float*)(smem + 18688);                 // 64
  float* al_lds = (float*)(smem + 18944);                 // 64
  float* gi_lds = (float*)(smem + 19200);                 // 192*4 f32

  const int g = blockIdx.x;
  // phase-2 role: batches 4*p2..+3, dims 64*q2..+63
  const int p2 = g >> 3, q2 = g & 7;
  const int b_loc = tid >> 6, dl = tid & 63;
  const int bg = 4*p2 + b_loc, Dg = 64*q2 + dl;
  float hreg = h0[Dg];                       // own GRU state in a register
  int phase = 0;

  for (int i = 0; i < 48; ++i) {
    // =========================== phase 1 ===================================
    if (g < 32) {
      // ---- attention for batch g (reads ring chunk (i,g)) ----
      if (tid == 0) {
        while (ld_a32(pd + (i*32 + g)) == 0u) __builtin_amdgcn_s_sleep(2);
      }
      { int t2 = tid * 2;
        unsigned long long v = ld_a64(h + g*512 + t2);
        hsm[t2] = lo_f(v); hsm[t2+1] = hi_f(v); }
      __syncthreads();
      const char* ringc = (const char*)(ring + ((size_t)((i % RW)*32 + g))*65536);
      const int s = tid >> 2, p = tid & 3;
      // issue P loads (16 x 16B), then Qt loads (16 x 16B); wait for P only.
      u32x4 pb[16], qb[16];
      {
        const char* pbase = ringc + s*1024 + p*256;
        #pragma unroll
        for (int it = 0; it < 16; ++it) ld16u(pb[it], pbase + it*16);
        const char* qbase = ringc + 65536 + (size_t)(tid*2)*128;
        #pragma unroll
        for (int it = 0; it < 16; ++it) ld16u(qb[it], qbase + it*16);
      }
      vm_wait16();
      {
        const float* qp = hsm + p*128;
        float sum = 0.f;
        #pragma unroll
        for (int it = 0; it < 16; ++it) {
          u32x4 u = pb[it];
          float2 f0 = bf2f(u[0]), f1 = bf2f(u[1]), f2 = bf2f(u[2]), f3 = bf2f(u[3]);
          const float* qq = qp + it*8;
          sum += f0.x*qq[0] + f0.y*qq[1] + f1.x*qq[2] + f1.y*qq[3]
               + f2.x*qq[4] + f2.y*qq[5] + f3.x*qq[6] + f3.y*qq[7];
        }
        sum += __shfl_xor(sum, 1);
        sum += __shfl_xor(sum, 2);
        if (p == 0) {
          int len = lengths[g*48 + i];
          sc_lds[s] = (s < len) ? sum : -1e30f;
        }
      }
      __syncthreads();
      if (tid < 64) {
        float v = sc_lds[tid];
        float mx = v;
        #pragma unroll
        for (int o = 32; o; o >>= 1) mx = fmaxf(mx, __shfl_xor(mx, o));
        float e = __expf(v - mx);
        float sm = e;
        #pragma unroll
        for (int o = 32; o; o >>= 1) sm += __shfl_xor(sm, o);
        al_lds[tid] = e * __builtin_amdgcn_rcpf(sm);
      }
      __syncthreads();
      vm_wait0();   // Qt prefetch registers valid ONLY after this (race fix)
      {
        const int d0 = tid * 2;
        float c0 = 0.f, c1 = 0.f;
        #pragma unroll
        for (int it = 0; it < 8; ++it) {
          u32x4 u = qb[it];                 // Qt row d0, s = it*8..+7
          const int s0 = it*8;
          float2 a0 = bf2f(u[0]), a1 = bf2f(u[1]), a2 = bf2f(u[2]), a3 = bf2f(u[3]);
          c0 += al_lds[s0]*a0.x + al_lds[s0+1]*a0.y + al_lds[s0+2]*a1.x + al_lds[s0+3]*a1.y
              + al_lds[s0+4]*a2.x + al_lds[s0+5]*a2.y + al_lds[s0+6]*a3.x + al_lds[s0+7]*a3.y;
        }
        #pragma unroll
        for (int it = 0; it < 8; ++it) {
          u32x4 u = qb[8+it];               // Qt row d0+1
          const int s0 = it*8;
          float2 a0 = bf2f(u[0]), a1 = bf2f(u[1]), a2 = bf2f(u[2]), a3 = bf2f(u[3]);
          c1 += al_lds[s0]*a0.x + al_lds[s0+1]*a0.y + al_lds[s0+2]*a1.x + al_lds[s0+3]*a1.y
              + al_lds[s0+4]*a2.x + al_lds[s0+5]*a2.y + al_lds[s0+6]*a3.x + al_lds[s0+7]*a3.y;
        }
        st_a32(xct + (size_t)d0*32 + g,     __builtin_bit_cast(unsigned, c0));
        st_a32(xct + (size_t)(d0+1)*32 + g, __builtin_bit_cast(unsigned, c1));
      }
    } else {
      // ---- hW GEMM: batches 8*pg..+7, WH rows 256*qg..+255 ----
      const int q3 = g - 32, pg = q3 >> 3, qg = q3 & 7;
      const int R0 = 256*qg;
      {
        const int r = tid >> 5, c32 = tid & 31;
        const char* src = (const char*)(hbf + (size_t)(8*pg + r)*512) + c32*32;
        u32x4 a, b2;
        ld16u(a, src); ld16u(b2, src + 16);
        vm_wait0();
        char* dst = (char*)x_lds + r*1040 + c32*32;
        *(u32x4*)dst = a; *(u32x4*)(dst + 16) = b2;
      }
      __syncthreads();
      f32x4 acc[4];
      #pragma unroll
      for (int t = 0; t < 4; ++t) acc[t] = (f32x4){0,0,0,0};
      const int Rw = R0 + 64*w;
      #pragma unroll
      for (int kt = 0; kt < 16; ++kt) {
        const int k = kt*32 + quad*8;
        bf16x8 a0 = *(const bf16x8*)((char*)x_lds + l15*1040 + k*2);
        #pragma unroll
        for (int nt = 0; nt < 4; ++nt) {
          bf16x8 bfr = *(const bf16x8*)(WH + (size_t)(Rw + nt*16 + l15)*512 + k);
          acc[nt] = MFMA16(a0, bfr, acc[nt]);
        }
      }
      if (quad < 2) {
        #pragma unroll
        for (int nt = 0; nt < 4; ++nt) {
          const int R = Rw + nt*16 + l15;
          if (R < 1536) {
            const float bias = b_hh[R];
            f32x4 vals = {acc[nt][0]+bias, acc[nt][1]+bias, acc[nt][2]+bias, acc[nt][3]+bias};
            st16(ght + (size_t)R*32 + 8*pg + quad*4, vals);
          } else {
            st16(hW2t + (size_t)(R - 1536)*32 + 8*pg + quad*4, acc[nt]);
          }
        }
      }
    }
    cbar(flags, rel, g, ++phase);

    // =========================== phase 2 ===================================
    // stage own 4 batches of xc/hW2 columns, x = tanh(xc+hW2) -> x_lds bf16
    {
      const int c = tid * 2;
      f32x4 xa, xb2, ha, hb2;
      ld16f(xa,  xct  + (size_t)c*32 + 4*p2);
      ld16f(ha,  hW2t + (size_t)c*32 + 4*p2);
      ld16f(xb2, xct  + (size_t)(c+1)*32 + 4*p2);
      ld16f(hb2, hW2t + (size_t)(c+1)*32 + 4*p2);
      vm_wait0();
      #pragma unroll
      for (int r = 0; r < 4; ++r) {
        float x0 = ftanh(xa[r] + ha[r]);
        float x1 = ftanh(xb2[r] + hb2[r]);
        *(unsigned*)((char*)x_lds + r*1040 + c*2) = pack_bf2(x0, x1);
      }
    }
    __syncthreads();
    {
      // gi slice: 192 W_ih rows {t*512 + 64*q2 + d : t in 0..2, d in 0..63}
      const bf16_t* wp[3];
      #pragma unroll
      for (int nt = 0; nt < 3; ++nt) {
        const int lr = w*48 + nt*16 + l15;
        wp[nt] = WI + ((size_t)((lr >> 6)*512 + 64*q2 + (lr & 63)))*512;
      }
      f32x4 ga[3];
      #pragma unroll
      for (int t = 0; t < 3; ++t) ga[t] = (f32x4){0,0,0,0};
      #pragma unroll
      for (int kt = 0; kt < 16; ++kt) {
        const int k = kt*32 + quad*8;
        bf16x8 a0 = *(const bf16x8*)((char*)x_lds + l15*1040 + k*2);
        #pragma unroll
        for (int nt = 0; nt < 3; ++nt) {
          bf16x8 bfr = *(const bf16x8*)(wp[nt] + k);
          ga[nt] = MFMA16(a0, bfr, ga[nt]);
        }
      }
      if (quad == 0) {
        #pragma unroll
        for (int nt = 0; nt < 3; ++nt) {
          const int lr = w*48 + nt*16 + l15;
          #pragma unroll
          for (int r = 0; r < 4; ++r) gi_lds[lr*4 + r] = ga[nt][r];
        }
      }
    }
    __syncthreads();
    {
      // GRU for own (4 batches x 64 dims) patch
      float ir = gi_lds[dl*4 + b_loc]        + b_ih[Dg];
      float iz = gi_lds[(64+dl)*4 + b_loc]   + b_ih[512 + Dg];
      float in = gi_lds[(128+dl)*4 + b_loc]  + b_ih[1024 + Dg];
      float hr = __builtin_bit_cast(float, ld_a32(ght + (size_t)Dg*32 + bg));
      float hz = __builtin_bit_cast(float, ld_a32(ght + (size_t)(512 + Dg)*32 + bg));
      float hn = __builtin_bit_cast(float, ld_a32(ght + (size_t)(1024 + Dg)*32 + bg));
      float rr = fsig(ir + hr);
      float zz = fsig(iz + hz);
      float nn = ftanh(in + rr * hn);
      float res = (1.f - zz) * nn + zz * hreg;
      hreg = res;
      if (i == 47) {
        out[bg*512 + Dg] = res;
      } else {
        float o2 = __shfl_xor(res, 1);
        if ((dl & 1) == 0) {
          st_a64(h + bg*512 + Dg, pack_f2(res, o2));
          st_a32(hbf + bg*512 + Dg, pack_bf2(res, o2));
        }
      }
    }
    if (i == 47) break;
    cbar(flags, rel, g, ++phase);
  }
}

// ======================= LEGACY PATH (fallback) =============================
__global__ __launch_bounds__(256) void prep_legacy(
    const float* __restrict__ Win, const float* __restrict__ Whh,
    const float* __restrict__ Wout, const float* __restrict__ Wih,
    bf16_t* __restrict__ WA, bf16_t* __restrict__ WoutB, bf16_t* __restrict__ WihB)
{
  int idx = blockIdx.x * 256 + threadIdx.x;
  if (idx < 262144)        WA[idx]            = (__bf16)Win[idx];
  else if (idx < 1048576)  WA[idx]            = (__bf16)Whh[idx - 262144];
  else if (idx < 1572864)  WoutB[idx-1048576] = (__bf16)Wout[idx - 1048576];
  else if (idx < 2359296)  WihB[idx-1572864]  = (__bf16)Wih[idx - 1572864];
}

__global__ __launch_bounds__(256) void embed_gemm(
    const int* __restrict__ cpt, const float* __restrict__ table,
    const float* __restrict__ Weh, const float* __restrict__ beh,
    bf16_t* __restrict__ mem)
{
  __shared__ unsigned short A_lds[64][40];
  __shared__ unsigned short B_lds[64][40];
  const int bid = blockIdx.x;
  const int M0 = (bid >> 3) * 64;
  const int N0 = (bid & 7) * 64;
  const int tid = threadIdx.x, lane = tid & 63, w = tid >> 6;
  const int l15 = lane & 15, quad = lane >> 4;
  const int srow = tid >> 2;
  const int koff = (tid & 3) * 8;
  const int tok = cpt[M0 + srow];
  const float* arow = table + (size_t)tok * 512;
  const float* brow = Weh + (size_t)(N0 + srow) * 512;

  f32x4 acc0 = {0,0,0,0}, acc1 = {0,0,0,0}, acc2 = {0,0,0,0}, acc3 = {0,0,0,0};
  for (int kt = 0; kt < 16; ++kt) {
    const int k0 = kt * 32;
    float4 alo = *(const float4*)(arow + k0 + koff);
    float4 ahi = *(const float4*)(arow + k0 + koff + 4);
    float4 blo = *(const float4*)(brow + k0 + koff);
    float4 bhi = *(const float4*)(brow + k0 + koff + 4);
    __syncthreads();
    *(bf16x8*)(&A_lds[srow][koff]) = cvt8(alo, ahi);
    *(bf16x8*)(&B_lds[srow][koff]) = cvt8(blo, bhi);
    __syncthreads();
    const int kq = quad * 8;
    bf16x8 bfr = *(const bf16x8*)(&B_lds[16*w + l15][kq]);
    bf16x8 a0 = *(const bf16x8*)(&A_lds[l15][kq]);
    bf16x8 a1 = *(const bf16x8*)(&A_lds[16 + l15][kq]);
    bf16x8 a2 = *(const bf16x8*)(&A_lds[32 + l15][kq]);
    bf16x8 a3 = *(const bf16x8*)(&A_lds[48 + l15][kq]);
    acc0 = MFMA16(a0, bfr, acc0);
    acc1 = MFMA16(a1, bfr, acc1);
    acc2 = MFMA16(a2, bfr, acc2);
    acc3 = MFMA16(a3, bfr, acc3);
  }
  const int n = N0 + 16*w + l15;
  const float bias = beh[n];
  f32x4 accs[4] = {acc0, acc1, acc2, acc3};
  #pragma unroll
  for (int mt = 0; mt < 4; ++mt) {
    #pragma unroll
    for (int r = 0; r < 4; ++r) {
      int m = M0 + mt*16 + quad*4 + r;
      float v = accs[mt][r] + bias;
      v = v > 0.f ? v : expm1f(v);
      int s = m & 63, nrow = m >> 6;
      int sent = nrow % 48, b = nrow / 48;
      mem[(((size_t)(sent*32 + b))*64 + s)*512 + n] = (__bf16)v;
    }
  }
}

__global__ __launch_bounds__(256) void scan_legacy(
    const bf16_t* __restrict__ mem, const int* __restrict__ lengths,
    const bf16_t* __restrict__ WA, const bf16_t* __restrict__ Wout, const bf16_t* __restrict__ Wih,
    const float* __restrict__ b_ih, const float* __restrict__ b_hh,
    float* __restrict__ q, float* __restrict__ gh,
    float* __restrict__ h, bf16_t* __restrict__ hbf,
    bf16_t* __restrict__ cbf, bf16_t* __restrict__ xbf,
    unsigned* __restrict__ bar, float* __restrict__ out)
{
  __shared__ __align__(16) unsigned char smem[52352];
  unsigned short* h_lds = (unsigned short*)smem;
  unsigned short* x_lds = (unsigned short*)smem;
  float* q_lds  = (float*)(smem + 33280);
  float* sc_lds = (float*)(smem + 35328);
  float* al_lds = (float*)(smem + 35584);
  unsigned short* c_lds = (unsigned short*)(smem + 33280);
  float* xb_lds = (float*)(smem + 50176);
  float* gi_lds = (float*)(smem + 33280);

  const int g = blockIdx.x, tid = threadIdx.x, lane = tid & 63, w = tid >> 6;
  const int quad = lane >> 4, l15 = lane & 15;
  int phase = 0;

  for (int i = 0; i < 48; ++i) {
    for (int it = 0; it < 16; ++it) {
      int chunk = tid + 256*it;
      int row = chunk >> 7, cc = chunk & 127;
      unsigned long long v = ld_a64(hbf + row*512 + cc*4);
      *(unsigned long long*)((char*)h_lds + row*1040 + cc*8) = v;
    }
    __syncthreads();
    {
      f32x4 acc0 = {0,0,0,0}, acc1 = {0,0,0,0};
      const int nrow = 64*g + 16*w + l15;
      const bf16_t* wrow = WA + (size_t)nrow * 512;
      #pragma unroll
      for (int kt = 0; kt < 16; ++kt) {
        const int k = kt*32 + quad*8;
        bf16x8 bfr = *(const bf16x8*)(wrow + k);
        bf16x8 a0 = *(const bf16x8*)((char*)h_lds + l15*1040 + k*2);
        bf16x8 a1 = *(const bf16x8*)((char*)h_lds + (16 + l15)*1040 + k*2);
        acc0 = MFMA16(a0, bfr, acc0);
        acc1 = MFMA16(a1, bfr, acc1);
      }
      const float bias = (nrow >= 512) ? b_hh[nrow - 512] : 0.f;
      #pragma unroll
      for (int r = 0; r < 4; ++r) {
        int b0 = quad*4 + r;
        float v0 = acc0[r] + bias, v1 = acc1[r] + bias;
        if (nrow < 512) {
          st_a32(q + b0*512 + nrow,        __builtin_bit_cast(unsigned, v0));
          st_a32(q + (b0+16)*512 + nrow,   __builtin_bit_cast(unsigned, v1));
        } else {
          st_a32(gh + b0*1536 + nrow-512,      __builtin_bit_cast(unsigned, v0));
          st_a32(gh + (b0+16)*1536 + nrow-512, __builtin_bit_cast(unsigned, v1));
        }
      }
    }
    gbar(bar, ++phase * 32);
    {
      for (int it = 0; it < 2; ++it) {
        int idx = tid + 256*it;
        unsigned v = ld_a32(q + g*512 + idx);
        q_lds[idx] = __builtin_bit_cast(float, v);
      }
      __syncthreads();
      const bf16_t* mrow = mem + ((size_t)(i*32 + g)) * 64 * 512;
      {
        const int s = tid >> 2, p = tid & 3;
        const uint4* mp = (const uint4*)(mrow + s*512 + p*128);
        const float* qp = q_lds + p*128;
        float sum = 0.f;
        #pragma unroll
        for (int it = 0; it < 16; ++it) {
          uint4 u = mp[it];
          float2 f0 = bf2f(u.x), f1 = bf2f(u.y), f2 = bf2f(u.z), f3 = bf2f(u.w);
          const float* qq = qp + it*8;
          sum += f0.x*qq[0] + f0.y*qq[1] + f1.x*qq[2] + f1.y*qq[3]
               + f2.x*qq[4] + f2.y*qq[5] + f3.x*qq[6] + f3.y*qq[7];
        }
        sum += __shfl_xor(sum, 1);
        sum += __shfl_xor(sum, 2);
        if (p == 0) {
          int len = lengths[g*48 + i];
          sc_lds[s] = (s < len) ? sum : -1e30f;
        }
      }
      __syncthreads();
      if (tid < 64) {
        float v = sc_lds[tid];
        float mx = v;
        #pragma unroll
        for (int o = 32; o; o >>= 1) mx = fmaxf(mx, __shfl_xor(mx, o));
        float e = __expf(v - mx);
        float sm = e;
        #pragma unroll
        for (int o = 32; o; o >>= 1) sm += __shfl_xor(sm, o);
        al_lds[tid] = e / sm;
      }
      __syncthreads();
      {
        const int d0 = tid * 2;
        float c0 = 0.f, c1 = 0.f;
        for (int s2 = 0; s2 < 64; ++s2) {
          unsigned u = *(const unsigned*)(mrow + s2*512 + d0);
          float2 f = bf2f(u);
          float a = al_lds[s2];
          c0 += a * f.x; c1 += a * f.y;
        }
        st_a32(cbf + g*512 + d0, pack_bf2(c0, c1));
      }
    }
    gbar(bar, ++phase * 32);
    {
      f32x4 acc = {0,0,0,0};
      const int nrow = 16*g + l15;
      const bf16_t* wrow = Wout + (size_t)nrow * 1024;
      for (int kh = 0; kh < 2; ++kh) {
        for (int it = 0; it < 8; ++it) {
          int cid = tid + 256*it;
          int row = cid >> 6, cc = cid & 63;
          unsigned long long v = ld_a64(cbf + row*512 + kh*256 + cc*4);
          *(unsigned long long*)((char*)c_lds + row*528 + cc*8) = v;
        }
        __syncthreads();
        if (w < 2) {
          #pragma unroll
          for (int kt = 0; kt < 8; ++kt) {
            const int kl = kt*32 + quad*8;
            bf16x8 bfr = *(const bf16x8*)(wrow + kh*256 + kl);
            bf16x8 af  = *(const bf16x8*)((char*)c_lds + (16*w + l15)*528 + kl*2);
            acc = MFMA16(af, bfr, acc);
          }
        }
        __syncthreads();
      }
      if (w < 2) {
        #pragma unroll
        for (int kt = 0; kt < 16; ++kt) {
          const int k = kt*32 + quad*8;
          bf16x8 bfr = *(const bf16x8*)(wrow + 512 + k);
          bf16x8 af  = *(const bf16x8*)((char*)h_lds + (16*w + l15)*1040 + k*2);
          acc = MFMA16(af, bfr, acc);
        }
        #pragma unroll
        for (int r = 0; r < 4; ++r)
          xb_lds[w*272 + l15*17 + quad*4 + r] = acc[r];
      }
      __syncthreads();
      {
        const int b = tid >> 3, np = tid & 7;
        const int mt = b >> 4, ml = b & 15;
        float v0 = ftanh(xb_lds[mt*272 + (2*np)*17 + ml]);
        float v1 = ftanh(xb_lds[mt*272 + (2*np+1)*17 + ml]);
        st_a32(xbf + b*512 + 16*g + 2*np, pack_bf2(v0, v1));
      }
    }
    gbar(bar, ++phase * 32);
    {
      for (int it = 0; it < 16; ++it) {
        int chunk = tid + 256*it;
        int row = chunk >> 7, cc = chunk & 127;
        unsigned long long v = ld_a64(xbf + row*512 + cc*4);
        *(unsigned long long*)((char*)x_lds + row*1040 + cc*8) = v;
      }
      __syncthreads();
      #pragma unroll
      for (int tt = 0; tt < 2; ++tt) {
        const int t = w + 4*tt;
        if (t < 6) {
          const int nt = t % 3, mt = t / 3;
          f32x4 acc = {0,0,0,0};
          const int nrow = nt*512 + 16*g + l15;
          const bf16_t* wrow = Wih + (size_t)nrow * 512;
          #pragma unroll
          for (int kt = 0; kt < 16; ++kt) {
            const int k = kt*32 + quad*8;
            bf16x8 bfr = *(const bf16x8*)(wrow + k);
            bf16x8 af  = *(const bf16x8*)((char*)x_lds + (16*mt + l15)*1040 + k*2);
            acc = MFMA16(af, bfr, acc);
          }
          #pragma unroll
          for (int r = 0; r < 4; ++r)
            gi_lds[t*272 + l15*17 + quad*4 + r] = acc[r];
        }
      }
      __syncthreads();
      {
        const int b = tid >> 3, dlp = tid & 7;
        const int mt = b >> 4, ml = b & 15;
        const int d0 = 16*g + 2*dlp;
        unsigned long long ur = ld_a64(gh + b*1536 + d0);
        unsigned long long uz = ld_a64(gh + b*1536 + 512 + d0);
        unsigned long long un = ld_a64(gh + b*1536 + 1024 + d0);
        unsigned long long uh = ld_a64(h + b*512 + d0);
        float res[2];
        #pragma unroll
        for (int e = 0; e < 2; ++e) {
          int dl = 2*dlp + e;
          float ir = gi_lds[(mt*3+0)*272 + dl*17 + ml] + b_ih[16*g + dl];
          float iz = gi_lds[(mt*3+1)*272 + dl*17 + ml] + b_ih[512 + 16*g + dl];
          float in = gi_lds[(mt*3+2)*272 + dl*17 + ml] + b_ih[1024 + 16*g + dl];
          float hr = e ? hi_f(ur) : lo_f(ur);
          float hz = e ? hi_f(uz) : lo_f(uz);
          float hn = e ? hi_f(un) : lo_f(un);
          float ho = e ? hi_f(uh) : lo_f(uh);
          float rr = fsig(ir + hr);
          float zz = fsig(iz + hz);
          float nn = ftanh(in + rr * hn);
          res[e] = (1.f - zz) * nn + zz * ho;
        }
        if (i == 47) {
          out[b*512 + d0]     = res[0];
          out[b*512 + d0 + 1] = res[1];
        } else {
          st_a64(h + b*512 + d0, pack_f2(res[0], res[1]));
          st_a32(hbf + b*512 + d0, pack_bf2(res[0], res[1]));
        }
      }
    }
    gbar(bar, ++phase * 32);
  }
}

// ---------------------------------------------------------------------------
extern "C" void kernel_launch(void* const* d_in, const int* in_sizes, int n_in,
                              void* d_out, int out_size, void* d_ws, size_t ws_size,
                              hipStream_t stream) {
  const int*   cpt   = (const int*)d_in[0];
  const float* table = (const float*)d_in[2];
  const float* Weh   = (const float*)d_in[3];
  const float* beh   = (const float*)d_in[4];
  const float* h0    = (const float*)d_in[5];
  const float* Win   = (const float*)d_in[6];
  const float* Wout  = (const float*)d_in[7];
  const float* Wih   = (const float*)d_in[8];
  const float* Whh   = (const float*)d_in[9];
  const float* bih   = (const float*)d_in[10];
  const float* bhh   = (const float*)d_in[11];
  char* ws = (char*)d_ws;

  if (ws_size >= WS_V4) {
    bf16_t* ring = (bf16_t*)(ws + V_RING);
    bf16_t* WehB = (bf16_t*)(ws + V_WEH);
    bf16_t* W2   = (bf16_t*)(ws + V_W2);
    bf16_t* WH   = (bf16_t*)(ws + V_WH);
    bf16_t* WI   = (bf16_t*)(ws + V_WI);
    int*    len  = (int*)(ws + V_LEN);
    float*  h    = (float*)(ws + V_H);
    bf16_t* hbf  = (bf16_t*)(ws + V_HBF);
    float*  ght  = (float*)(ws + V_GH);
    float*  hW2t = (float*)(ws + V_HW2);
    float*  xct  = (float*)(ws + V_XC);
    unsigned* flags = (unsigned*)(ws + V_FLG);
    unsigned* rel   = (unsigned*)(ws + V_REL);
    unsigned* pd    = (unsigned*)(ws + V_PD);

    hipMemsetAsync(ws + V_FLG, 0, 4096 + 64 + 6144, stream);
    prep_v4<<<10240, 256, 0, stream>>>(Weh, Win, Wout, Whh, Wih, WehB, W2, WH, WI);
    h_init<<<64, 256, 0, stream>>>(h0, h, hbf);
    lengths_kernel<<<6, 256, 0, stream>>>(cpt, len);
    fused_scan<<<256, 256, 0, stream>>>(cpt, table, beh, len,
                                        WehB, W2, WH, WI, bih, bhh, h0,
                                        ring, ght, hW2t, xct, h, hbf,
                                        flags, rel, pd, (float*)d_out);
  } else if (ws_size >= WS_LEG) {
    bf16_t* mem   = (bf16_t*)(ws + L_MEM);
    bf16_t* WA    = (bf16_t*)(ws + L_WA);
    bf16_t* WoutB = (bf16_t*)(ws + L_WOUT);
    bf16_t* WihB  = (bf16_t*)(ws + L_WIH);
    int*    len   = (int*)(ws + L_LEN);
    float*  h     = (float*)(ws + L_H);
    bf16_t* hbf   = (bf16_t*)(ws + L_HBF);
    float*  q     = (float*)(ws + L_Q);
    float*  gh    = (float*)(ws + L_GH);
    bf16_t* cbf   = (bf16_t*)(ws + L_CBF);
    bf16_t* xbf   = (bf16_t*)(ws + L_XBF);
    unsigned* bar = (unsigned*)(ws + L_BAR);

    hipMemsetAsync(bar, 0, 256, stream);
    prep_legacy<<<9216, 256, 0, stream>>>(Win, Whh, Wout, Wih, WA, WoutB, WihB);
    h_init<<<64, 256, 0, stream>>>(h0, h, hbf);
    lengths_kernel<<<6, 256, 0, stream>>>(cpt, len);
    embed_gemm<<<12288, 256, 0, stream>>>(cpt, table, Weh, beh, mem);
    scan_legacy<<<32, 256, 0, stream>>>(mem, len, WA, WoutB, WihB, bih, bhh,
                                        q, gh, h, hbf, cbf, xbf, bar, (float*)d_out);
  }
}